// Round 13
// baseline (1314.367 us; speedup 1.0000x reference)
//
#include <hip/hip_runtime.h>

// ProportionalAttentionWrapper on MI355X (gfx950), fp16 MFMA pipeline (fp32 accum).
// B=2, S=4096, C=1024, H=16, DH=64. out = softmax(QK^T * 64^0.25 + log(ts)) V, proj.
// R13 = R12 + in-block split-K attention (R10's structure, exonerated: R10/R11 NaN
// was v_max3_f32, removed). 8 waves/block: waves 0-3 keys [0,2048), waves 4-7 keys
// [2048,4096), LDS merge of (O,l,m) partials. 2x waves/SIMD -> MFMA||VALU overlap.
// Workspace layout (bytes), total 75,530,240:
//   [0, 16M)            x_fp16 [8192][1024]  (reused as attn_out [B][S][C] fp16)
//   [16M, 24M)          Wt q/k/v/o fp16 [1024][1024] each
//   [24M(25165824), +3*16M) q' [bh][s][d] (pre-scaled), k [bh][s][d], V'^T [bh][d][s]
//   [75497472, +16KB)   ts fp16 [B][S]

typedef unsigned short u16;
typedef unsigned int u32;
typedef _Float16 f16x8 __attribute__((ext_vector_type(8)));
typedef float f32x4 __attribute__((ext_vector_type(4)));
typedef short short4v __attribute__((ext_vector_type(4)));

constexpr int SEQ = 4096, CDIM = 1024, NH = 16, DHE = 64;
// 64^0.25 * log2(e): folded into Q so QK^T emits base-2 exponents directly
constexpr float SCALE2 = 2.8284271247461903f * 1.4426950408889634f;

template <int N> struct IC { static constexpr int v = N; };

union Frag { f16x8 v; short4v h[2]; };

__device__ __forceinline__ u16 f2h(float f) {
  union { _Float16 h; u16 u; } x;
  x.h = (_Float16)f;
  return x.u;
}

__device__ __forceinline__ u32 pkrtz(float a, float b) {
  u32 r;
  asm("v_cvt_pkrtz_f16_f32 %0, %1, %2" : "=v"(r) : "v"(a), "v"(b));
  return r;
}

__device__ __forceinline__ short4v pk4(const f32x4& v) {
  union { u32 w[2]; short4v s; } u;
  u.w[0] = pkrtz(v[0], v[1]);
  u.w[1] = pkrtz(v[2], v[3]);
  return u.s;
}

__device__ __forceinline__ float exp2fast(float x) {
  float r;
  asm("v_exp_f32 %0, %1" : "=v"(r) : "v"(x));
  return r;
}

__device__ __forceinline__ f32x4 mfma16(const Frag& a, const Frag& b, f32x4 c) {
  return __builtin_amdgcn_mfma_f32_16x16x32_f16(a.v, b.v, c, 0, 0, 0);
}

// async HBM -> LDS, 16B per lane; LDS dest = wave-uniform base + lane*16
__device__ __forceinline__ void gl16(const void* g, void* l) {
  __builtin_amdgcn_global_load_lds(
      (const __attribute__((address_space(1))) u32*)g,
      (__attribute__((address_space(3))) u32*)l, 16, 0, 0);
}

// ---- prep kernels -----------------------------------------------------------

__global__ void cast_x_kernel(const float* __restrict__ x, u16* __restrict__ out) {
  size_t i = ((size_t)blockIdx.x * 256 + threadIdx.x) * 8;
  float4 a = *(const float4*)(x + i);
  float4 b = *(const float4*)(x + i + 4);
  uint4 o;
  o.x = (u32)f2h(a.x) | ((u32)f2h(a.y) << 16);
  o.y = (u32)f2h(a.z) | ((u32)f2h(a.w) << 16);
  o.z = (u32)f2h(b.x) | ((u32)f2h(b.y) << 16);
  o.w = (u32)f2h(b.z) | ((u32)f2h(b.w) << 16);
  *(uint4*)(out + i) = o;
}

__global__ __launch_bounds__(256) void transpose_w4_kernel(
    const float* __restrict__ Wq, const float* __restrict__ Wk,
    const float* __restrict__ Wv, const float* __restrict__ Wo,
    u16* __restrict__ dq, u16* __restrict__ dk,
    u16* __restrict__ dv, u16* __restrict__ dow) {
  __shared__ float tile[64][65];
  const float* src;
  u16* dst;
  switch (blockIdx.z) {
    case 0: src = Wq; dst = dq; break;
    case 1: src = Wk; dst = dk; break;
    case 2: src = Wv; dst = dv; break;
    default: src = Wo; dst = dow; break;
  }
  const int r0 = blockIdx.y * 64, c0 = blockIdx.x * 64;
  const int tx = threadIdx.x & 63, ty = threadIdx.x >> 6;
#pragma unroll
  for (int i = 0; i < 16; ++i) {
    const int row = i * 4 + ty;
    tile[row][tx] = src[(size_t)(r0 + row) * 1024 + c0 + tx];
  }
  __syncthreads();
#pragma unroll
  for (int i = 0; i < 16; ++i) {
    const int row = i * 4 + ty;
    dst[(size_t)(c0 + row) * 1024 + r0 + tx] = f2h(tile[tx][row]);
  }
}

__global__ void tscast_kernel(const int* __restrict__ ts, u16* __restrict__ out) {
  int i = blockIdx.x * 256 + threadIdx.x;
  out[i] = f2h((float)ts[i]);   // exact for 1..16
}

// ---- GEMM: C[M,N] = A[M,K] * Bt[N,K]^T, M=8192, K=1024 ----------------------
// global_load_lds staging: LDS [128][32 halfs] linear; source 16B chunk per lane
// pre-permuted by (t&3)^((t>>3)&3); reads XOR 16B slot with (row>>1)&3.
// XCD swizzle: flat id -> (id&7)*chunk + id>>3, so each XCD gets contiguous work.
// EPI=0: N=3072; q*SCALE2, k plain ([bh][s][d]); v*ts transposed [bh][d][s].
// EPI=1: fp32 out + bias.  NBX: grid x-dim (24 or 8), compile-time for fast div.

template <int EPI, int NBX>
__global__ __launch_bounds__(256) void gemm_f16(const u16* __restrict__ A,
                                                const u16* __restrict__ Bt,
                                                void* __restrict__ Out,
                                                const float* __restrict__ bias,
                                                const int* __restrict__ ts) {
  __shared__ __align__(16) short Alds[128 * 32];
  __shared__ __align__(16) short Blds[128 * 32];
  const int t = threadIdx.x;
  // XCD-aware remap (total blocks = NBX*64, divisible by 8)
  const int fid = blockIdx.x + NBX * blockIdx.y;
  constexpr int CPX = NBX * 64 / 8;
  const int wid = (fid & 7) * CPX + (fid >> 3);
  const int bnb = wid % NBX;    // N/128 block
  const int bm = wid / NBX;     // M/128 block
  const int lane = t & 63, wv = t >> 6;
  const int wm = wv >> 1, wn = wv & 1;
  const int l16 = lane & 15, lq = lane >> 4;

  f32x4 acc[4][4];
  f32x4 z = {0.f, 0.f, 0.f, 0.f};
#pragma unroll
  for (int i = 0; i < 4; ++i)
#pragma unroll
    for (int j = 0; j < 4; ++j) acc[i][j] = z;

  // staging: call c covers rows c*64 + (t>>2); lane writes LDS slot t&3 of its row
  const int srow = t >> 2;
  const int schunk = (t & 3) ^ ((t >> 3) & 3);
  const u16* Ag = A + (size_t)(bm * 128 + srow) * 1024 + schunk * 8;
  const u16* Bg = Bt + (size_t)(bnb * 128 + srow) * 1024 + schunk * 8;
  short* Ad = Alds + (t >> 6) * 512;   // wave-uniform
  short* Bd = Blds + (t >> 6) * 512;

  // frag read offsets (halfs), slot ^ (row>>1)&3 swizzle
  const int m2 = (l16 >> 1) & 3;
  const int o0 = (((lq >> 1) ^ m2) * 8) + (lq & 1) * 4;
  const int o1 = ((((lq >> 1) | 2) ^ m2) * 8) + (lq & 1) * 4;

  for (int kb = 0; kb < 32; ++kb) {
    const int k0 = kb * 32;
    gl16(Ag + k0, Ad);
    gl16(Ag + 64 * 1024 + k0, Ad + 2048);
    gl16(Bg + k0, Bd);
    gl16(Bg + 64 * 1024 + k0, Bd + 2048);
    __syncthreads();   // drains vmcnt -> LDS tile complete

    Frag af[4], bf[4];
#pragma unroll
    for (int am = 0; am < 4; ++am) {
      const short* p = Alds + (wm * 64 + am * 16 + l16) * 32;
      af[am].h[0] = *(const short4v*)(p + o0);
      af[am].h[1] = *(const short4v*)(p + o1);
    }
#pragma unroll
    for (int bn = 0; bn < 4; ++bn) {
      const short* p = Blds + (wn * 64 + bn * 16 + l16) * 32;
      bf[bn].h[0] = *(const short4v*)(p + o0);
      bf[bn].h[1] = *(const short4v*)(p + o1);
    }
#pragma unroll
    for (int am = 0; am < 4; ++am)
#pragma unroll
      for (int bn = 0; bn < 4; ++bn) acc[am][bn] = mfma16(af[am], bf[bn], acc[am][bn]);
    __syncthreads();
  }

#pragma unroll
  for (int am = 0; am < 4; ++am) {
#pragma unroll
    for (int bn = 0; bn < 4; ++bn) {
#pragma unroll
      for (int r = 0; r < 4; ++r) {
        const int m = bm * 128 + wm * 64 + am * 16 + lq * 4 + r;  // D row map
        const int n = bnb * 128 + wn * 64 + bn * 16 + l16;        // D col map
        float vsum = acc[am][bn][r];
        if (EPI == 0) {
          const int which = n >> 10;           // 0=q 1=k 2=v
          const int nn = n & 1023;
          const int h = nn >> 6, d = nn & 63;
          const int b = m >> 12, s = m & 4095;
          const int bhh = b * NH + h;
          size_t addr;
          if (which == 2) {  // V' = ts*V, stored transposed [bh][d][s]
            vsum *= (float)ts[b * SEQ + s];
            addr = (size_t)2 * 8388608 + ((size_t)bhh * DHE + d) * SEQ + s;
          } else {
            if (which == 0) vsum *= SCALE2;    // scale folded into Q
            addr = (size_t)which * 8388608 + ((size_t)bhh * SEQ + s) * DHE + d;
          }
          ((u16*)Out)[addr] = f2h(vsum);
        } else {
          ((float*)Out)[(size_t)m * 1024 + n] = vsum + bias[n];
        }
      }
    }
  }
}

// ---- flash attention --------------------------------------------------------
// grid 512 (XCD-swizzled), block 512 (8 waves). Waves 0-3 (grp 0): keys [0,2048);
// waves 4-7 (grp 1): keys [2048,4096). Per wave: 64 q-rows, 32 K-tiles of 64 keys.
// Per-group double-buffered padded K/V LDS (R12 layout). End: grp1 partials
// (O, lsum, m) merged into grp0 via LDS scratch (Klds reused), grp0 writes out.

__global__ __launch_bounds__(512, 4) void attn_kernel(const u16* __restrict__ Q,
                                                      const u16* __restrict__ K,
                                                      const u16* __restrict__ Vt,
                                                      const u16* __restrict__ ts16,
                                                      u16* __restrict__ Out) {
  __shared__ __align__(16) short Klds[2][2][64][72];   // [grp][dbuf]
  __shared__ __align__(16) short Vtlds[2][2][64][72];  // [grp][dbuf][d][key^sw]

  const int t = threadIdx.x;
  // XCD-aware remap: 512 blocks, blocks on XCD x get bid in [x*64, x*64+64)
  const int bid = (blockIdx.x & 7) * 64 + (blockIdx.x >> 3);
  const int bh = bid >> 4;          // 32 (B*H); 4 heads per XCD
  const int qb = bid & 15;          // 16 q-blocks of 256
  const int lane = t & 63;
  const int grp = t >> 8;           // key-half
  const int tg = t & 255;           // thread within group
  const int wvg = (t >> 6) & 3;     // wave within group
  const int l16 = lane & 15, lq = lane >> 4;
  const int b = bh >> 4, h = bh & 15;

  // Q fragments (B operand for swapped QK^T), four 16-row quarters per wave
  Frag qf[4][2];
#pragma unroll
  for (int qh = 0; qh < 4; ++qh) {
    const int qrow = qb * 256 + wvg * 64 + qh * 16 + l16;
    const u16* qp = Q + ((size_t)bh * SEQ + qrow) * DHE;
#pragma unroll
    for (int f = 0; f < 2; ++f) {
      qf[qh][f].h[0] = *(const short4v*)(qp + f * 32 + lq * 4);
      qf[qh][f].h[1] = *(const short4v*)(qp + f * 32 + lq * 4 + 16);
    }
  }

  float mrow[4] = {0.f, 0.f, 0.f, 0.f};   // running max (base-2), per q = l16
  f32x4 lsum[4];
  f32x4 oacc[4][4];                        // [qh][dd]
  f32x4 z = {0.f, 0.f, 0.f, 0.f};
#pragma unroll
  for (int qh = 0; qh < 4; ++qh) {
    lsum[qh] = z;
#pragma unroll
    for (int d = 0; d < 4; ++d) oacc[qh][d] = z;
  }

  // staging geometry (per group: 256 threads stage the group's 64-key tile)
  const int a7 = tg & 7, sd = a7 * 8, skey = tg >> 3;    // K: rows skey/skey+32
  const int vd = tg >> 2, voct = (tg & 3) * 8;           // V^T: row d=vd
  const int vsw = ((vd >> 3) & 7) << 3;                  // XOR swizzle (8-granular)

  const int keyoff = grp * 2048;                         // group's key range
  const u16* Kbase = K + (size_t)bh * SEQ * DHE + (size_t)keyoff * DHE;
  const u16* Vtbase = Vt + ((size_t)bh * DHE + vd) * SEQ + keyoff;
  const u16* tsb = ts16 + b * SEQ + keyoff;

  // prologue: stage tile 0 into regs
  uint4 kv0 = *(const uint4*)(Kbase + (size_t)skey * DHE + sd);
  uint4 kv1 = *(const uint4*)(Kbase + (size_t)(skey + 32) * DHE + sd);
  uint4 vv0 = *(const uint4*)(Vtbase + voct);
  uint4 vv1 = *(const uint4*)(Vtbase + voct + 32);

  Frag tsfr[2];
  Frag paf[4][2];
  f32x4 scA[4], scB[4];

  for (int kt = 0; kt < 32; ++kt) {
    short (*Kb)[72] = Klds[grp][kt & 1];
    short (*Vb)[72] = Vtlds[grp][kt & 1];
    *(uint4*)&Kb[skey][sd] = kv0;
    *(uint4*)&Kb[skey + 32][sd] = kv1;
    *(uint4*)&Vb[vd][voct ^ vsw] = vv0;
    *(uint4*)&Vb[vd][(voct + 32) ^ vsw] = vv1;

    // issue next tile's global loads (complete during compute)
    if (kt < 31) {
      const u16* Kn = Kbase + (size_t)(kt + 1) * 64 * DHE + (size_t)skey * DHE + sd;
      kv0 = *(const uint4*)(Kn);
      kv1 = *(const uint4*)(Kn + 32 * DHE);
      const u16* Vn = Vtbase + (kt + 1) * 64 + voct;
      vv0 = *(const uint4*)(Vn);
      vv1 = *(const uint4*)(Vn + 32);
    }
    __syncthreads();   // single barrier per iter (double-buffered)

    // ts fragments for this tile (B operand: value ts_key at k=key)
    {
      const u16* tst = tsb + kt * 64;
#pragma unroll
      for (int kh = 0; kh < 2; ++kh) {
        tsfr[kh].h[0] = *(const short4v*)(tst + kh * 32 + lq * 4);
        tsfr[kh].h[1] = *(const short4v*)(tst + kh * 32 + lq * 4 + 16);
      }
    }

    // K fragments once per tile, shared by all 4 q-quarters
    Frag kfr[4][2];
#pragma unroll
    for (int k2 = 0; k2 < 4; ++k2) {
#pragma unroll
      for (int f = 0; f < 2; ++f) {
        const short* p = &Kb[k2 * 16 + l16][f * 32 + lq * 4];
        kfr[k2][f].h[0] = *(const short4v*)p;
        kfr[k2][f].h[1] = *(const short4v*)(p + 16);
      }
    }

    auto qkq = [&](auto qc, f32x4 (&sc)[4]) {
      constexpr int qh = decltype(qc)::v;
      const float nm = -mrow[qh];
      f32x4 seed = {nm, nm, nm, nm};
#pragma unroll
      for (int k2 = 0; k2 < 4; ++k2) {
        f32x4 a = mfma16(kfr[k2][0], qf[qh][0], seed);
        sc[k2] = mfma16(kfr[k2][1], qf[qh][1], a);
      }
    };

    auto smq = [&](auto qc, f32x4 (&sc)[4]) {
      constexpr int qh = decltype(qc)::v;
      float hm[4];
#pragma unroll
      for (int k2 = 0; k2 < 4; ++k2) {
        const f32x4 s = sc[k2];
        hm[k2] = fmaxf(fmaxf(s[0], s[1]), fmaxf(s[2], s[3]));
      }
      float mx = fmaxf(fmaxf(hm[0], hm[1]), fmaxf(hm[2], hm[3]));
      mx = fmaxf(mx, __shfl_xor(mx, 16));
      mx = fmaxf(mx, __shfl_xor(mx, 32));
      if (__any(mx > 8.f)) {                 // wave-uniform rescale (rare)
        const float sh = fmaxf(mx, 0.f);     // never lower m
        const float al = exp2fast(-sh);
        mrow[qh] += sh;
        f32x4 alv;
#pragma unroll
        for (int r = 0; r < 4; ++r) alv[r] = __shfl(al, lq * 4 + r, 16);
#pragma unroll
        for (int dd = 0; dd < 4; ++dd) oacc[qh][dd] *= alv;
        lsum[qh] *= alv;
#pragma unroll
        for (int k2 = 0; k2 < 4; ++k2) sc[k2] -= sh;
      }
#pragma unroll
      for (int k2 = 0; k2 < 4; ++k2) {
        f32x4 s = sc[k2];
#pragma unroll
        for (int r = 0; r < 4; ++r) s[r] = exp2fast(s[r]);
        sc[k2] = s;
      }
      paf[qh][0].h[0] = pk4(sc[0]); paf[qh][0].h[1] = pk4(sc[1]);
      paf[qh][1].h[0] = pk4(sc[2]); paf[qh][1].h[1] = pk4(sc[3]);
      // lsum += sum_k ts_k * P_k (owner layout: reg r = q-row lq*4+r)
      lsum[qh] = mfma16(paf[qh][0], tsfr[0], lsum[qh]);
      lsum[qh] = mfma16(paf[qh][1], tsfr[1], lsum[qh]);
    };

    // quarter pipeline: SM(q) VALU/exp overlaps QK(q+1) MFMA cluster
    qkq(IC<0>{}, scA);
    qkq(IC<1>{}, scB);
    smq(IC<0>{}, scA);
    qkq(IC<2>{}, scA);
    smq(IC<1>{}, scB);
    qkq(IC<3>{}, scB);
    smq(IC<2>{}, scA);
    smq(IC<3>{}, scB);

    // O += P V' (V fragments read once, feed all 4 q-quarters)
    __builtin_amdgcn_s_setprio(1);
#pragma unroll
    for (int dd = 0; dd < 4; ++dd) {
      const int vrow = dd * 16 + l16;
      const int e = ((vrow >> 3) & 7) << 3;
#pragma unroll
      for (int kh = 0; kh < 2; ++kh) {
        Frag vb;
        vb.h[0] = *(const short4v*)&Vb[vrow][(kh * 32 + lq * 4) ^ e];
        vb.h[1] = *(const short4v*)&Vb[vrow][(kh * 32 + 16 + lq * 4) ^ e];
#pragma unroll
        for (int qh = 0; qh < 4; ++qh)
          oacc[qh][dd] = mfma16(paf[qh][kh], vb, oacc[qh][dd]);
      }
    }
    __builtin_amdgcn_s_setprio(0);
  }

  // ---- merge grp1 partials into grp0 via LDS scratch (Klds reused) ----------
  // scratch floats: O [wvg][lane][16] (16KB), L at +4096 [wvg][lane][4] (4KB),
  // M at +5120 [wvg][16] (256B)
  float* sm = (float*)&Klds[0][0][0][0];
#pragma unroll
  for (int qh = 0; qh < 4; ++qh) {
    __syncthreads();
    if (grp == 1) {
      float* po = sm + (wvg * 64 + lane) * 16;
#pragma unroll
      for (int dd = 0; dd < 4; ++dd) *(f32x4*)(po + dd * 4) = oacc[qh][dd];
      *(f32x4*)(sm + 4096 + (wvg * 64 + lane) * 4) = lsum[qh];
      if (lq == 0) sm[5120 + wvg * 16 + l16] = mrow[qh];
    }
    __syncthreads();
    if (grp == 0) {
      const float mB = sm[5120 + wvg * 16 + l16];
      const float mA = mrow[qh];
      const float mx = fmaxf(mA, mB);
      const float aA = exp2fast(mA - mx), aB = exp2fast(mB - mx);
      f32x4 aAr, aBr;
#pragma unroll
      for (int r = 0; r < 4; ++r) {
        aAr[r] = __shfl(aA, lq * 4 + r, 16);
        aBr[r] = __shfl(aB, lq * 4 + r, 16);
      }
      const float* po = sm + (wvg * 64 + lane) * 16;
      f32x4 lB = *(const f32x4*)(sm + 4096 + (wvg * 64 + lane) * 4);
      lsum[qh] = lsum[qh] * aAr + lB * aBr;
#pragma unroll
      for (int dd = 0; dd < 4; ++dd) {
        f32x4 oB = *(const f32x4*)(po + dd * 4);
        oacc[qh][dd] = oacc[qh][dd] * aAr + oB * aBr;
      }
    }
  }

  // write attn output merged-head [B][S][C] fp16 (grp0 only)
  if (grp == 0) {
#pragma unroll
    for (int qh = 0; qh < 4; ++qh) {
      f32x4 linv;
#pragma unroll
      for (int r = 0; r < 4; ++r) linv[r] = 1.f / lsum[qh][r];
#pragma unroll
      for (int dd = 0; dd < 4; ++dd) {
#pragma unroll
        for (int r = 0; r < 4; ++r) {
          const int row = qb * 256 + wvg * 64 + qh * 16 + lq * 4 + r;
          const float v = oacc[qh][dd][r] * linv[r];
          Out[((size_t)b * SEQ + row) * CDIM + h * DHE + dd * 16 + l16] = f2h(v);
        }
      }
    }
  }
}

// ---- launcher ---------------------------------------------------------------

extern "C" void kernel_launch(void* const* d_in, const int* in_sizes, int n_in,
                              void* d_out, int out_size, void* d_ws, size_t ws_size,
                              hipStream_t stream) {
  const float* hs = (const float*)d_in[0];
  const float* Wq = (const float*)d_in[1];
  const float* Wk = (const float*)d_in[2];
  const float* Wv = (const float*)d_in[3];
  const float* Wo = (const float*)d_in[4];
  const float* bo = (const float*)d_in[5];
  const int* ts = (const int*)d_in[6];
  float* out = (float*)d_out;

  char* ws = (char*)d_ws;
  u16* xf = (u16*)(ws);                     // 16,777,216 B; reused as attn_out
  u16* wtq = (u16*)(ws + 16777216);         // q/k/v Wt contiguous -> one N=3072 GEMM
  u16* wtk = (u16*)(ws + 18874368);
  u16* wtv = (u16*)(ws + 20971520);
  u16* wto = (u16*)(ws + 23068672);
  u16* qbuf = (u16*)(ws + 25165824);        // q',k,V'^T contiguous (8,388,608 each)
  u16* kbuf = (u16*)(ws + 41943040);
  u16* vtbuf = (u16*)(ws + 58720256);       // V'^T [bh][d][s]
  u16* ts16 = (u16*)(ws + 75497472);        // ts fp16 [B][S]

  cast_x_kernel<<<4096, 256, 0, stream>>>(hs, xf);
  transpose_w4_kernel<<<dim3(16, 16, 4), 256, 0, stream>>>(Wq, Wk, Wv, Wo,
                                                           wtq, wtk, wtv, wto);
  tscast_kernel<<<32, 256, 0, stream>>>(ts, ts16);

  // fused QKV projection (q pre-scaled, V' = ts*V written transposed)
  gemm_f16<0, 24><<<dim3(24, 64), 256, 0, stream>>>(xf, wtq, (void*)qbuf, nullptr, ts);

  attn_kernel<<<512, 512, 0, stream>>>(qbuf, kbuf, vtbuf, ts16, xf);

  // output projection + bias
  gemm_f16<1, 8><<<dim3(8, 64), 256, 0, stream>>>(xf, wto, (void*)out, bo, nullptr);

  (void)in_sizes; (void)n_in; (void)out_size; (void)ws_size;
}

// Round 14
// 328.318 us; speedup vs baseline: 4.0033x; 4.0033x over previous
//
#include <hip/hip_runtime.h>

// ProportionalAttentionWrapper on MI355X (gfx950), fp16 MFMA pipeline (fp32 accum).
// B=2, S=4096, C=1024, H=16, DH=64. out = softmax(QK^T * 64^0.25 + log(ts)) V, proj.
// R14 = R12 attn (proven 198us, XCD-swizzled) + double-buffered GEMM staging:
// STAGE(kb+1) issued before compute(kb), single barrier/iter (T3 2-phase recipe)
// -> HBM latency of global_load_lds hides under the 32-MFMA block.
// (R13 lesson: per-wave state ~230 regs pins attn at 2 waves/SIMD; forced cap spills.)
// Workspace layout (bytes), total 75,530,240:
//   [0, 16M)            x_fp16 [8192][1024]  (reused as attn_out [B][S][C] fp16)
//   [16M, 24M)          Wt q/k/v/o fp16 [1024][1024] each
//   [24M(25165824), +3*16M) q' [bh][s][d] (pre-scaled), k [bh][s][d], V'^T [bh][d][s]
//   [75497472, +16KB)   ts fp16 [B][S]

typedef unsigned short u16;
typedef unsigned int u32;
typedef _Float16 f16x8 __attribute__((ext_vector_type(8)));
typedef float f32x4 __attribute__((ext_vector_type(4)));
typedef short short4v __attribute__((ext_vector_type(4)));

constexpr int SEQ = 4096, CDIM = 1024, NH = 16, DHE = 64;
// 64^0.25 * log2(e): folded into Q so QK^T emits base-2 exponents directly
constexpr float SCALE2 = 2.8284271247461903f * 1.4426950408889634f;

template <int N> struct IC { static constexpr int v = N; };

union Frag { f16x8 v; short4v h[2]; };

__device__ __forceinline__ u16 f2h(float f) {
  union { _Float16 h; u16 u; } x;
  x.h = (_Float16)f;
  return x.u;
}

__device__ __forceinline__ u32 pkrtz(float a, float b) {
  u32 r;
  asm("v_cvt_pkrtz_f16_f32 %0, %1, %2" : "=v"(r) : "v"(a), "v"(b));
  return r;
}

__device__ __forceinline__ short4v pk4(const f32x4& v) {
  union { u32 w[2]; short4v s; } u;
  u.w[0] = pkrtz(v[0], v[1]);
  u.w[1] = pkrtz(v[2], v[3]);
  return u.s;
}

__device__ __forceinline__ float exp2fast(float x) {
  float r;
  asm("v_exp_f32 %0, %1" : "=v"(r) : "v"(x));
  return r;
}

__device__ __forceinline__ f32x4 mfma16(const Frag& a, const Frag& b, f32x4 c) {
  return __builtin_amdgcn_mfma_f32_16x16x32_f16(a.v, b.v, c, 0, 0, 0);
}

// async HBM -> LDS, 16B per lane; LDS dest = wave-uniform base + lane*16
__device__ __forceinline__ void gl16(const void* g, void* l) {
  __builtin_amdgcn_global_load_lds(
      (const __attribute__((address_space(1))) u32*)g,
      (__attribute__((address_space(3))) u32*)l, 16, 0, 0);
}

// ---- prep kernels -----------------------------------------------------------

__global__ void cast_x_kernel(const float* __restrict__ x, u16* __restrict__ out) {
  size_t i = ((size_t)blockIdx.x * 256 + threadIdx.x) * 8;
  float4 a = *(const float4*)(x + i);
  float4 b = *(const float4*)(x + i + 4);
  uint4 o;
  o.x = (u32)f2h(a.x) | ((u32)f2h(a.y) << 16);
  o.y = (u32)f2h(a.z) | ((u32)f2h(a.w) << 16);
  o.z = (u32)f2h(b.x) | ((u32)f2h(b.y) << 16);
  o.w = (u32)f2h(b.z) | ((u32)f2h(b.w) << 16);
  *(uint4*)(out + i) = o;
}

__global__ __launch_bounds__(256) void transpose_w4_kernel(
    const float* __restrict__ Wq, const float* __restrict__ Wk,
    const float* __restrict__ Wv, const float* __restrict__ Wo,
    u16* __restrict__ dq, u16* __restrict__ dk,
    u16* __restrict__ dv, u16* __restrict__ dow) {
  __shared__ float tile[64][65];
  const float* src;
  u16* dst;
  switch (blockIdx.z) {
    case 0: src = Wq; dst = dq; break;
    case 1: src = Wk; dst = dk; break;
    case 2: src = Wv; dst = dv; break;
    default: src = Wo; dst = dow; break;
  }
  const int r0 = blockIdx.y * 64, c0 = blockIdx.x * 64;
  const int tx = threadIdx.x & 63, ty = threadIdx.x >> 6;
#pragma unroll
  for (int i = 0; i < 16; ++i) {
    const int row = i * 4 + ty;
    tile[row][tx] = src[(size_t)(r0 + row) * 1024 + c0 + tx];
  }
  __syncthreads();
#pragma unroll
  for (int i = 0; i < 16; ++i) {
    const int row = i * 4 + ty;
    dst[(size_t)(c0 + row) * 1024 + r0 + tx] = f2h(tile[tx][row]);
  }
}

__global__ void tscast_kernel(const int* __restrict__ ts, u16* __restrict__ out) {
  int i = blockIdx.x * 256 + threadIdx.x;
  out[i] = f2h((float)ts[i]);   // exact for 1..16
}

// ---- GEMM: C[M,N] = A[M,K] * Bt[N,K]^T, M=8192, K=1024 ----------------------
// Double-buffered global_load_lds staging (T3 2-phase): STAGE(kb+1) issued before
// compute(kb); one barrier per iter. LDS [2][128][32 halfs] linear; source 16B
// chunk pre-permuted by (t&3)^((t>>3)&3); reads XOR 16B slot with (row>>1)&3.
// XCD swizzle: flat id -> (id&7)*chunk + id>>3. EPI=0: N=3072; q*SCALE2, k plain,
// v*ts transposed [bh][d][s]. EPI=1: fp32 out + bias.

template <int EPI, int NBX>
__global__ __launch_bounds__(256) void gemm_f16(const u16* __restrict__ A,
                                                const u16* __restrict__ Bt,
                                                void* __restrict__ Out,
                                                const float* __restrict__ bias,
                                                const int* __restrict__ ts) {
  __shared__ __align__(16) short Alds[2][128 * 32];
  __shared__ __align__(16) short Blds[2][128 * 32];
  const int t = threadIdx.x;
  // XCD-aware remap (total blocks = NBX*64, divisible by 8)
  const int fid = blockIdx.x + NBX * blockIdx.y;
  constexpr int CPX = NBX * 64 / 8;
  const int wid = (fid & 7) * CPX + (fid >> 3);
  const int bnb = wid % NBX;    // N/128 block
  const int bm = wid / NBX;     // M/128 block
  const int lane = t & 63, wv = t >> 6;
  const int wm = wv >> 1, wn = wv & 1;
  const int l16 = lane & 15, lq = lane >> 4;

  f32x4 acc[4][4];
  f32x4 z = {0.f, 0.f, 0.f, 0.f};
#pragma unroll
  for (int i = 0; i < 4; ++i)
#pragma unroll
    for (int j = 0; j < 4; ++j) acc[i][j] = z;

  // staging: call c covers rows c*64 + (t>>2); lane writes LDS slot t&3 of its row
  const int srow = t >> 2;
  const int schunk = (t & 3) ^ ((t >> 3) & 3);
  const u16* Ag = A + (size_t)(bm * 128 + srow) * 1024 + schunk * 8;
  const u16* Bg = Bt + (size_t)(bnb * 128 + srow) * 1024 + schunk * 8;
  const int dof = (t >> 6) * 512;   // wave-uniform LDS offset

  auto stage = [&](int kb, int bufi) {
    const int k0 = kb * 32;
    short* Ad = &Alds[bufi][0] + dof;
    short* Bd = &Blds[bufi][0] + dof;
    gl16(Ag + k0, Ad);
    gl16(Ag + 64 * 1024 + k0, Ad + 2048);
    gl16(Bg + k0, Bd);
    gl16(Bg + 64 * 1024 + k0, Bd + 2048);
  };

  // frag read offsets (halfs), slot ^ (row>>1)&3 swizzle
  const int m2 = (l16 >> 1) & 3;
  const int o0 = (((lq >> 1) ^ m2) * 8) + (lq & 1) * 4;
  const int o1 = ((((lq >> 1) | 2) ^ m2) * 8) + (lq & 1) * 4;

  stage(0, 0);
  __syncthreads();   // drains vmcnt -> buf0 ready

  for (int kb = 0; kb < 32; ++kb) {
    if (kb < 31) stage(kb + 1, (kb + 1) & 1);   // issue next tile (overlaps compute)
    const short* Ab = &Alds[kb & 1][0];
    const short* Bb = &Blds[kb & 1][0];

    Frag af[4], bf[4];
#pragma unroll
    for (int am = 0; am < 4; ++am) {
      const short* p = Ab + (wm * 64 + am * 16 + l16) * 32;
      af[am].h[0] = *(const short4v*)(p + o0);
      af[am].h[1] = *(const short4v*)(p + o1);
    }
#pragma unroll
    for (int bn = 0; bn < 4; ++bn) {
      const short* p = Bb + (wn * 64 + bn * 16 + l16) * 32;
      bf[bn].h[0] = *(const short4v*)(p + o0);
      bf[bn].h[1] = *(const short4v*)(p + o1);
    }
#pragma unroll
    for (int am = 0; am < 4; ++am)
#pragma unroll
      for (int bn = 0; bn < 4; ++bn) acc[am][bn] = mfma16(af[am], bf[bn], acc[am][bn]);
    __syncthreads();   // drains this iter's stage; next tile ready
  }

#pragma unroll
  for (int am = 0; am < 4; ++am) {
#pragma unroll
    for (int bn = 0; bn < 4; ++bn) {
#pragma unroll
      for (int r = 0; r < 4; ++r) {
        const int m = bm * 128 + wm * 64 + am * 16 + lq * 4 + r;  // D row map
        const int n = bnb * 128 + wn * 64 + bn * 16 + l16;        // D col map
        float vsum = acc[am][bn][r];
        if (EPI == 0) {
          const int which = n >> 10;           // 0=q 1=k 2=v
          const int nn = n & 1023;
          const int h = nn >> 6, d = nn & 63;
          const int b = m >> 12, s = m & 4095;
          const int bhh = b * NH + h;
          size_t addr;
          if (which == 2) {  // V' = ts*V, stored transposed [bh][d][s]
            vsum *= (float)ts[b * SEQ + s];
            addr = (size_t)2 * 8388608 + ((size_t)bhh * DHE + d) * SEQ + s;
          } else {
            if (which == 0) vsum *= SCALE2;    // scale folded into Q
            addr = (size_t)which * 8388608 + ((size_t)bhh * SEQ + s) * DHE + d;
          }
          ((u16*)Out)[addr] = f2h(vsum);
        } else {
          ((float*)Out)[(size_t)m * 1024 + n] = vsum + bias[n];
        }
      }
    }
  }
}

// ---- flash attention (R12, unchanged) ---------------------------------------
// grid 512 (XCD-swizzled: each XCD owns 4 heads -> K/V fetched once per L2).
// 4 waves x 64 q-rows = 256 q-rows/block, KBLK=64. Reg-staged K/V, padded
// [64][72] double-buffered LDS, 1 barrier/iter. Quarter pipeline; PV shared.

__global__ __launch_bounds__(256, 2) void attn_kernel(const u16* __restrict__ Q,
                                                      const u16* __restrict__ K,
                                                      const u16* __restrict__ Vt,
                                                      const u16* __restrict__ ts16,
                                                      u16* __restrict__ Out) {
  __shared__ __align__(16) short Klds[2][64][72];
  __shared__ __align__(16) short Vtlds[2][64][72];  // [d][key ^ ((d>>3)<<3)]

  const int t = threadIdx.x;
  // XCD-aware remap: 512 blocks, blocks on XCD x get bid in [x*64, x*64+64)
  const int bid = (blockIdx.x & 7) * 64 + (blockIdx.x >> 3);
  const int bh = bid >> 4;          // 32 (B*H); 4 heads per XCD
  const int qb = bid & 15;          // 16 q-blocks of 256
  const int lane = t & 63, wv = t >> 6;
  const int l16 = lane & 15, lq = lane >> 4;
  const int b = bh >> 4, h = bh & 15;

  // Q fragments (B operand for swapped QK^T), four 16-row quarters per wave
  Frag qf[4][2];
#pragma unroll
  for (int qh = 0; qh < 4; ++qh) {
    const int qrow = qb * 256 + wv * 64 + qh * 16 + l16;
    const u16* qp = Q + ((size_t)bh * SEQ + qrow) * DHE;
#pragma unroll
    for (int f = 0; f < 2; ++f) {
      qf[qh][f].h[0] = *(const short4v*)(qp + f * 32 + lq * 4);
      qf[qh][f].h[1] = *(const short4v*)(qp + f * 32 + lq * 4 + 16);
    }
  }

  float mrow[4] = {0.f, 0.f, 0.f, 0.f};   // running max (base-2), per q = l16
  f32x4 lsum[4];
  f32x4 oacc[4][4];                        // [qh][dd]
  f32x4 z = {0.f, 0.f, 0.f, 0.f};
#pragma unroll
  for (int qh = 0; qh < 4; ++qh) {
    lsum[qh] = z;
#pragma unroll
    for (int d = 0; d < 4; ++d) oacc[qh][d] = z;
  }

  // staging geometry
  const int a7 = t & 7, sd = a7 * 8, skey = t >> 3;      // K: rows skey/skey+32
  const int vd = t >> 2, voct = (t & 3) * 8;             // V^T: row d=vd
  const int vsw = ((vd >> 3) & 7) << 3;                  // XOR swizzle (8-granular)

  const u16* Kbase = K + (size_t)bh * SEQ * DHE;
  const u16* Vtbase = Vt + ((size_t)bh * DHE + vd) * SEQ;
  const u16* tsb = ts16 + b * SEQ;

  // prologue: stage tile 0 into regs
  uint4 kv0 = *(const uint4*)(Kbase + (size_t)skey * DHE + sd);
  uint4 kv1 = *(const uint4*)(Kbase + (size_t)(skey + 32) * DHE + sd);
  uint4 vv0 = *(const uint4*)(Vtbase + voct);
  uint4 vv1 = *(const uint4*)(Vtbase + voct + 32);

  Frag tsfr[2];
  Frag paf[4][2];
  f32x4 scA[4], scB[4];

  for (int kt = 0; kt < 64; ++kt) {
    short (*Kb)[72] = Klds[kt & 1];
    short (*Vb)[72] = Vtlds[kt & 1];
    *(uint4*)&Kb[skey][sd] = kv0;
    *(uint4*)&Kb[skey + 32][sd] = kv1;
    *(uint4*)&Vb[vd][voct ^ vsw] = vv0;
    *(uint4*)&Vb[vd][(voct + 32) ^ vsw] = vv1;

    // issue next tile's global loads (complete during compute)
    if (kt < 63) {
      const u16* Kn = Kbase + (size_t)(kt + 1) * 64 * DHE + (size_t)skey * DHE + sd;
      kv0 = *(const uint4*)(Kn);
      kv1 = *(const uint4*)(Kn + 32 * DHE);
      const u16* Vn = Vtbase + (kt + 1) * 64 + voct;
      vv0 = *(const uint4*)(Vn);
      vv1 = *(const uint4*)(Vn + 32);
    }
    __syncthreads();   // single barrier per iter (double-buffered)

    // ts fragments for this tile (B operand: value ts_key at k=key)
    {
      const u16* tst = tsb + kt * 64;
#pragma unroll
      for (int kh = 0; kh < 2; ++kh) {
        tsfr[kh].h[0] = *(const short4v*)(tst + kh * 32 + lq * 4);
        tsfr[kh].h[1] = *(const short4v*)(tst + kh * 32 + lq * 4 + 16);
      }
    }

    // K fragments once per tile, shared by all 4 q-quarters
    Frag kfr[4][2];
#pragma unroll
    for (int k2 = 0; k2 < 4; ++k2) {
#pragma unroll
      for (int f = 0; f < 2; ++f) {
        const short* p = &Kb[k2 * 16 + l16][f * 32 + lq * 4];
        kfr[k2][f].h[0] = *(const short4v*)p;
        kfr[k2][f].h[1] = *(const short4v*)(p + 16);
      }
    }

    auto qkq = [&](auto qc, f32x4 (&sc)[4]) {
      constexpr int qh = decltype(qc)::v;
      const float nm = -mrow[qh];
      f32x4 seed = {nm, nm, nm, nm};
#pragma unroll
      for (int k2 = 0; k2 < 4; ++k2) {
        f32x4 a = mfma16(kfr[k2][0], qf[qh][0], seed);
        sc[k2] = mfma16(kfr[k2][1], qf[qh][1], a);
      }
    };

    auto smq = [&](auto qc, f32x4 (&sc)[4]) {
      constexpr int qh = decltype(qc)::v;
      float hm[4];
#pragma unroll
      for (int k2 = 0; k2 < 4; ++k2) {
        const f32x4 s = sc[k2];
        hm[k2] = fmaxf(fmaxf(s[0], s[1]), fmaxf(s[2], s[3]));
      }
      float mx = fmaxf(fmaxf(hm[0], hm[1]), fmaxf(hm[2], hm[3]));
      mx = fmaxf(mx, __shfl_xor(mx, 16));
      mx = fmaxf(mx, __shfl_xor(mx, 32));
      if (__any(mx > 8.f)) {                 // wave-uniform rescale (rare)
        const float sh = fmaxf(mx, 0.f);     // never lower m
        const float al = exp2fast(-sh);
        mrow[qh] += sh;
        f32x4 alv;
#pragma unroll
        for (int r = 0; r < 4; ++r) alv[r] = __shfl(al, lq * 4 + r, 16);
#pragma unroll
        for (int dd = 0; dd < 4; ++dd) oacc[qh][dd] *= alv;
        lsum[qh] *= alv;
#pragma unroll
        for (int k2 = 0; k2 < 4; ++k2) sc[k2] -= sh;
      }
#pragma unroll
      for (int k2 = 0; k2 < 4; ++k2) {
        f32x4 s = sc[k2];
#pragma unroll
        for (int r = 0; r < 4; ++r) s[r] = exp2fast(s[r]);
        sc[k2] = s;
      }
      paf[qh][0].h[0] = pk4(sc[0]); paf[qh][0].h[1] = pk4(sc[1]);
      paf[qh][1].h[0] = pk4(sc[2]); paf[qh][1].h[1] = pk4(sc[3]);
      // lsum += sum_k ts_k * P_k (owner layout: reg r = q-row lq*4+r)
      lsum[qh] = mfma16(paf[qh][0], tsfr[0], lsum[qh]);
      lsum[qh] = mfma16(paf[qh][1], tsfr[1], lsum[qh]);
    };

    // quarter pipeline: SM(q) VALU/exp overlaps QK(q+1) MFMA cluster
    qkq(IC<0>{}, scA);
    qkq(IC<1>{}, scB);
    smq(IC<0>{}, scA);
    qkq(IC<2>{}, scA);
    smq(IC<1>{}, scB);
    qkq(IC<3>{}, scB);
    smq(IC<2>{}, scA);
    smq(IC<3>{}, scB);

    // O += P V' (V fragments read once, feed all 4 q-quarters)
    __builtin_amdgcn_s_setprio(1);
#pragma unroll
    for (int dd = 0; dd < 4; ++dd) {
      const int vrow = dd * 16 + l16;
      const int e = ((vrow >> 3) & 7) << 3;
#pragma unroll
      for (int kh = 0; kh < 2; ++kh) {
        Frag vb;
        vb.h[0] = *(const short4v*)&Vb[vrow][(kh * 32 + lq * 4) ^ e];
        vb.h[1] = *(const short4v*)&Vb[vrow][(kh * 32 + 16 + lq * 4) ^ e];
#pragma unroll
        for (int qh = 0; qh < 4; ++qh)
          oacc[qh][dd] = mfma16(paf[qh][kh], vb, oacc[qh][dd]);
      }
    }
    __builtin_amdgcn_s_setprio(0);
  }

  // write attn output merged-head [B][S][C] fp16 (lsum already owner-layout)
#pragma unroll
  for (int qh = 0; qh < 4; ++qh) {
    f32x4 linv;
#pragma unroll
    for (int r = 0; r < 4; ++r) linv[r] = 1.f / lsum[qh][r];
#pragma unroll
    for (int dd = 0; dd < 4; ++dd) {
#pragma unroll
      for (int r = 0; r < 4; ++r) {
        const int row = qb * 256 + wv * 64 + qh * 16 + lq * 4 + r;
        const float v = oacc[qh][dd][r] * linv[r];
        Out[((size_t)b * SEQ + row) * CDIM + h * DHE + dd * 16 + l16] = f2h(v);
      }
    }
  }
}

// ---- launcher ---------------------------------------------------------------

extern "C" void kernel_launch(void* const* d_in, const int* in_sizes, int n_in,
                              void* d_out, int out_size, void* d_ws, size_t ws_size,
                              hipStream_t stream) {
  const float* hs = (const float*)d_in[0];
  const float* Wq = (const float*)d_in[1];
  const float* Wk = (const float*)d_in[2];
  const float* Wv = (const float*)d_in[3];
  const float* Wo = (const float*)d_in[4];
  const float* bo = (const float*)d_in[5];
  const int* ts = (const int*)d_in[6];
  float* out = (float*)d_out;

  char* ws = (char*)d_ws;
  u16* xf = (u16*)(ws);                     // 16,777,216 B; reused as attn_out
  u16* wtq = (u16*)(ws + 16777216);         // q/k/v Wt contiguous -> one N=3072 GEMM
  u16* wtk = (u16*)(ws + 18874368);
  u16* wtv = (u16*)(ws + 20971520);
  u16* wto = (u16*)(ws + 23068672);
  u16* qbuf = (u16*)(ws + 25165824);        // q',k,V'^T contiguous (8,388,608 each)
  u16* kbuf = (u16*)(ws + 41943040);
  u16* vtbuf = (u16*)(ws + 58720256);       // V'^T [bh][d][s]
  u16* ts16 = (u16*)(ws + 75497472);        // ts fp16 [B][S]

  cast_x_kernel<<<4096, 256, 0, stream>>>(hs, xf);
  transpose_w4_kernel<<<dim3(16, 16, 4), 256, 0, stream>>>(Wq, Wk, Wv, Wo,
                                                           wtq, wtk, wtv, wto);
  tscast_kernel<<<32, 256, 0, stream>>>(ts, ts16);

  // fused QKV projection (q pre-scaled, V' = ts*V written transposed)
  gemm_f16<0, 24><<<dim3(24, 64), 256, 0, stream>>>(xf, wtq, (void*)qbuf, nullptr, ts);

  attn_kernel<<<512, 256, 0, stream>>>(qbuf, kbuf, vtbuf, ts16, xf);

  // output projection + bias
  gemm_f16<1, 8><<<dim3(8, 64), 256, 0, stream>>>(xf, wto, (void*)out, bo, nullptr);

  (void)in_sizes; (void)n_in; (void)out_size; (void)ws_size;
}

// Round 15
// 320.530 us; speedup vs baseline: 4.1006x; 1.0243x over previous
//
#include <hip/hip_runtime.h>

// ProportionalAttentionWrapper on MI355X (gfx950), fp16 MFMA pipeline (fp32 accum).
// B=2, S=4096, C=1024, H=16, DH=64. out = softmax(QK^T * 64^0.25 + log(ts)) V, proj.
// R15 = R14 + all three prep kernels fused into one launch (blockIdx-range dispatch)
// -> 6 kernels to 4, saving launch gaps + tail under-utilization.
// Component state: attn 198us (issue-bound plateau, 2 waves/SIMD VGPR-pinned),
// gemm<0> ~60us (~860TF, at m97-structure ceiling), gemm<1> ~27us (part write-bound).
// Workspace layout (bytes), total 75,530,240:
//   [0, 16M)            x_fp16 [8192][1024]  (reused as attn_out [B][S][C] fp16)
//   [16M, 24M)          Wt q/k/v/o fp16 [1024][1024] each
//   [24M(25165824), +3*16M) q' [bh][s][d] (pre-scaled), k [bh][s][d], V'^T [bh][d][s]
//   [75497472, +16KB)   ts fp16 [B][S]

typedef unsigned short u16;
typedef unsigned int u32;
typedef _Float16 f16x8 __attribute__((ext_vector_type(8)));
typedef float f32x4 __attribute__((ext_vector_type(4)));
typedef short short4v __attribute__((ext_vector_type(4)));

constexpr int SEQ = 4096, CDIM = 1024, NH = 16, DHE = 64;
// 64^0.25 * log2(e): folded into Q so QK^T emits base-2 exponents directly
constexpr float SCALE2 = 2.8284271247461903f * 1.4426950408889634f;

template <int N> struct IC { static constexpr int v = N; };

union Frag { f16x8 v; short4v h[2]; };

__device__ __forceinline__ u16 f2h(float f) {
  union { _Float16 h; u16 u; } x;
  x.h = (_Float16)f;
  return x.u;
}

__device__ __forceinline__ u32 pkrtz(float a, float b) {
  u32 r;
  asm("v_cvt_pkrtz_f16_f32 %0, %1, %2" : "=v"(r) : "v"(a), "v"(b));
  return r;
}

__device__ __forceinline__ short4v pk4(const f32x4& v) {
  union { u32 w[2]; short4v s; } u;
  u.w[0] = pkrtz(v[0], v[1]);
  u.w[1] = pkrtz(v[2], v[3]);
  return u.s;
}

__device__ __forceinline__ float exp2fast(float x) {
  float r;
  asm("v_exp_f32 %0, %1" : "=v"(r) : "v"(x));
  return r;
}

__device__ __forceinline__ f32x4 mfma16(const Frag& a, const Frag& b, f32x4 c) {
  return __builtin_amdgcn_mfma_f32_16x16x32_f16(a.v, b.v, c, 0, 0, 0);
}

// async HBM -> LDS, 16B per lane; LDS dest = wave-uniform base + lane*16
__device__ __forceinline__ void gl16(const void* g, void* l) {
  __builtin_amdgcn_global_load_lds(
      (const __attribute__((address_space(1))) u32*)g,
      (__attribute__((address_space(3))) u32*)l, 16, 0, 0);
}

// ---- fused prep kernel ------------------------------------------------------
// blocks [0,4096): cast x fp32->fp16 (8 elems/thread)
// blocks [4096,5120): tiled transpose+cast of Wq/Wk/Wv/Wo (64x64 f32 tiles)
// blocks [5120,5152): ts int -> fp16
// Branch is block-uniform; __syncthreads in transpose branch is uniform-per-block.

__global__ __launch_bounds__(256) void prep_kernel(
    const float* __restrict__ x, u16* __restrict__ xout,
    const float* __restrict__ Wq, const float* __restrict__ Wk,
    const float* __restrict__ Wv, const float* __restrict__ Wo,
    u16* __restrict__ dq, u16* __restrict__ dk,
    u16* __restrict__ dv, u16* __restrict__ dow,
    const int* __restrict__ ts, u16* __restrict__ tsout) {
  __shared__ float tile[64][65];
  const int bidx = blockIdx.x;
  if (bidx < 4096) {
    size_t i = ((size_t)bidx * 256 + threadIdx.x) * 8;
    float4 a = *(const float4*)(x + i);
    float4 b = *(const float4*)(x + i + 4);
    uint4 o;
    o.x = (u32)f2h(a.x) | ((u32)f2h(a.y) << 16);
    o.y = (u32)f2h(a.z) | ((u32)f2h(a.w) << 16);
    o.z = (u32)f2h(b.x) | ((u32)f2h(b.y) << 16);
    o.w = (u32)f2h(b.z) | ((u32)f2h(b.w) << 16);
    *(uint4*)(xout + i) = o;
  } else if (bidx < 5120) {
    const int idx = bidx - 4096;
    const int z = idx >> 8, rem = idx & 255;
    const float* src;
    u16* dst;
    switch (z) {
      case 0: src = Wq; dst = dq; break;
      case 1: src = Wk; dst = dk; break;
      case 2: src = Wv; dst = dv; break;
      default: src = Wo; dst = dow; break;
    }
    const int r0 = (rem >> 4) * 64, c0 = (rem & 15) * 64;
    const int tx = threadIdx.x & 63, ty = threadIdx.x >> 6;
#pragma unroll
    for (int i = 0; i < 16; ++i) {
      const int row = i * 4 + ty;
      tile[row][tx] = src[(size_t)(r0 + row) * 1024 + c0 + tx];
    }
    __syncthreads();
#pragma unroll
    for (int i = 0; i < 16; ++i) {
      const int row = i * 4 + ty;
      dst[(size_t)(c0 + row) * 1024 + r0 + tx] = f2h(tile[tx][row]);
    }
  } else {
    const int i = (bidx - 5120) * 256 + threadIdx.x;
    tsout[i] = f2h((float)ts[i]);   // exact for 1..16
  }
}

// ---- GEMM: C[M,N] = A[M,K] * Bt[N,K]^T, M=8192, K=1024 ----------------------
// Double-buffered global_load_lds staging (T3 2-phase): STAGE(kb+1) issued before
// compute(kb); one barrier per iter. LDS [2][128][32 halfs] linear; source 16B
// chunk pre-permuted by (t&3)^((t>>3)&3); reads XOR 16B slot with (row>>1)&3.
// XCD swizzle: flat id -> (id&7)*chunk + id>>3. EPI=0: N=3072; q*SCALE2, k plain,
// v*ts transposed [bh][d][s]. EPI=1: fp32 out + bias.

template <int EPI, int NBX>
__global__ __launch_bounds__(256) void gemm_f16(const u16* __restrict__ A,
                                                const u16* __restrict__ Bt,
                                                void* __restrict__ Out,
                                                const float* __restrict__ bias,
                                                const int* __restrict__ ts) {
  __shared__ __align__(16) short Alds[2][128 * 32];
  __shared__ __align__(16) short Blds[2][128 * 32];
  const int t = threadIdx.x;
  // XCD-aware remap (total blocks = NBX*64, divisible by 8)
  const int fid = blockIdx.x + NBX * blockIdx.y;
  constexpr int CPX = NBX * 64 / 8;
  const int wid = (fid & 7) * CPX + (fid >> 3);
  const int bnb = wid % NBX;    // N/128 block
  const int bm = wid / NBX;     // M/128 block
  const int lane = t & 63, wv = t >> 6;
  const int wm = wv >> 1, wn = wv & 1;
  const int l16 = lane & 15, lq = lane >> 4;

  f32x4 acc[4][4];
  f32x4 z = {0.f, 0.f, 0.f, 0.f};
#pragma unroll
  for (int i = 0; i < 4; ++i)
#pragma unroll
    for (int j = 0; j < 4; ++j) acc[i][j] = z;

  // staging: call c covers rows c*64 + (t>>2); lane writes LDS slot t&3 of its row
  const int srow = t >> 2;
  const int schunk = (t & 3) ^ ((t >> 3) & 3);
  const u16* Ag = A + (size_t)(bm * 128 + srow) * 1024 + schunk * 8;
  const u16* Bg = Bt + (size_t)(bnb * 128 + srow) * 1024 + schunk * 8;
  const int dof = (t >> 6) * 512;   // wave-uniform LDS offset

  auto stage = [&](int kb, int bufi) {
    const int k0 = kb * 32;
    short* Ad = &Alds[bufi][0] + dof;
    short* Bd = &Blds[bufi][0] + dof;
    gl16(Ag + k0, Ad);
    gl16(Ag + 64 * 1024 + k0, Ad + 2048);
    gl16(Bg + k0, Bd);
    gl16(Bg + 64 * 1024 + k0, Bd + 2048);
  };

  // frag read offsets (halfs), slot ^ (row>>1)&3 swizzle
  const int m2 = (l16 >> 1) & 3;
  const int o0 = (((lq >> 1) ^ m2) * 8) + (lq & 1) * 4;
  const int o1 = ((((lq >> 1) | 2) ^ m2) * 8) + (lq & 1) * 4;

  stage(0, 0);
  __syncthreads();   // drains vmcnt -> buf0 ready

  for (int kb = 0; kb < 32; ++kb) {
    if (kb < 31) stage(kb + 1, (kb + 1) & 1);   // issue next tile (overlaps compute)
    const short* Ab = &Alds[kb & 1][0];
    const short* Bb = &Blds[kb & 1][0];

    Frag af[4], bf[4];
#pragma unroll
    for (int am = 0; am < 4; ++am) {
      const short* p = Ab + (wm * 64 + am * 16 + l16) * 32;
      af[am].h[0] = *(const short4v*)(p + o0);
      af[am].h[1] = *(const short4v*)(p + o1);
    }
#pragma unroll
    for (int bn = 0; bn < 4; ++bn) {
      const short* p = Bb + (wn * 64 + bn * 16 + l16) * 32;
      bf[bn].h[0] = *(const short4v*)(p + o0);
      bf[bn].h[1] = *(const short4v*)(p + o1);
    }
#pragma unroll
    for (int am = 0; am < 4; ++am)
#pragma unroll
      for (int bn = 0; bn < 4; ++bn) acc[am][bn] = mfma16(af[am], bf[bn], acc[am][bn]);
    __syncthreads();   // drains this iter's stage; next tile ready
  }

#pragma unroll
  for (int am = 0; am < 4; ++am) {
#pragma unroll
    for (int bn = 0; bn < 4; ++bn) {
#pragma unroll
      for (int r = 0; r < 4; ++r) {
        const int m = bm * 128 + wm * 64 + am * 16 + lq * 4 + r;  // D row map
        const int n = bnb * 128 + wn * 64 + bn * 16 + l16;        // D col map
        float vsum = acc[am][bn][r];
        if (EPI == 0) {
          const int which = n >> 10;           // 0=q 1=k 2=v
          const int nn = n & 1023;
          const int h = nn >> 6, d = nn & 63;
          const int b = m >> 12, s = m & 4095;
          const int bhh = b * NH + h;
          size_t addr;
          if (which == 2) {  // V' = ts*V, stored transposed [bh][d][s]
            vsum *= (float)ts[b * SEQ + s];
            addr = (size_t)2 * 8388608 + ((size_t)bhh * DHE + d) * SEQ + s;
          } else {
            if (which == 0) vsum *= SCALE2;    // scale folded into Q
            addr = (size_t)which * 8388608 + ((size_t)bhh * SEQ + s) * DHE + d;
          }
          ((u16*)Out)[addr] = f2h(vsum);
        } else {
          ((float*)Out)[(size_t)m * 1024 + n] = vsum + bias[n];
        }
      }
    }
  }
}

// ---- flash attention (R12, unchanged) ---------------------------------------
// grid 512 (XCD-swizzled: each XCD owns 4 heads -> K/V fetched once per L2).
// 4 waves x 64 q-rows = 256 q-rows/block, KBLK=64. Reg-staged K/V, padded
// [64][72] double-buffered LDS, 1 barrier/iter. Quarter pipeline; PV shared.

__global__ __launch_bounds__(256, 2) void attn_kernel(const u16* __restrict__ Q,
                                                      const u16* __restrict__ K,
                                                      const u16* __restrict__ Vt,
                                                      const u16* __restrict__ ts16,
                                                      u16* __restrict__ Out) {
  __shared__ __align__(16) short Klds[2][64][72];
  __shared__ __align__(16) short Vtlds[2][64][72];  // [d][key ^ ((d>>3)<<3)]

  const int t = threadIdx.x;
  // XCD-aware remap: 512 blocks, blocks on XCD x get bid in [x*64, x*64+64)
  const int bid = (blockIdx.x & 7) * 64 + (blockIdx.x >> 3);
  const int bh = bid >> 4;          // 32 (B*H); 4 heads per XCD
  const int qb = bid & 15;          // 16 q-blocks of 256
  const int lane = t & 63, wv = t >> 6;
  const int l16 = lane & 15, lq = lane >> 4;
  const int b = bh >> 4, h = bh & 15;

  // Q fragments (B operand for swapped QK^T), four 16-row quarters per wave
  Frag qf[4][2];
#pragma unroll
  for (int qh = 0; qh < 4; ++qh) {
    const int qrow = qb * 256 + wv * 64 + qh * 16 + l16;
    const u16* qp = Q + ((size_t)bh * SEQ + qrow) * DHE;
#pragma unroll
    for (int f = 0; f < 2; ++f) {
      qf[qh][f].h[0] = *(const short4v*)(qp + f * 32 + lq * 4);
      qf[qh][f].h[1] = *(const short4v*)(qp + f * 32 + lq * 4 + 16);
    }
  }

  float mrow[4] = {0.f, 0.f, 0.f, 0.f};   // running max (base-2), per q = l16
  f32x4 lsum[4];
  f32x4 oacc[4][4];                        // [qh][dd]
  f32x4 z = {0.f, 0.f, 0.f, 0.f};
#pragma unroll
  for (int qh = 0; qh < 4; ++qh) {
    lsum[qh] = z;
#pragma unroll
    for (int d = 0; d < 4; ++d) oacc[qh][d] = z;
  }

  // staging geometry
  const int a7 = t & 7, sd = a7 * 8, skey = t >> 3;      // K: rows skey/skey+32
  const int vd = t >> 2, voct = (t & 3) * 8;             // V^T: row d=vd
  const int vsw = ((vd >> 3) & 7) << 3;                  // XOR swizzle (8-granular)

  const u16* Kbase = K + (size_t)bh * SEQ * DHE;
  const u16* Vtbase = Vt + ((size_t)bh * DHE + vd) * SEQ;
  const u16* tsb = ts16 + b * SEQ;

  // prologue: stage tile 0 into regs
  uint4 kv0 = *(const uint4*)(Kbase + (size_t)skey * DHE + sd);
  uint4 kv1 = *(const uint4*)(Kbase + (size_t)(skey + 32) * DHE + sd);
  uint4 vv0 = *(const uint4*)(Vtbase + voct);
  uint4 vv1 = *(const uint4*)(Vtbase + voct + 32);

  Frag tsfr[2];
  Frag paf[4][2];
  f32x4 scA[4], scB[4];

  for (int kt = 0; kt < 64; ++kt) {
    short (*Kb)[72] = Klds[kt & 1];
    short (*Vb)[72] = Vtlds[kt & 1];
    *(uint4*)&Kb[skey][sd] = kv0;
    *(uint4*)&Kb[skey + 32][sd] = kv1;
    *(uint4*)&Vb[vd][voct ^ vsw] = vv0;
    *(uint4*)&Vb[vd][(voct + 32) ^ vsw] = vv1;

    // issue next tile's global loads (complete during compute)
    if (kt < 63) {
      const u16* Kn = Kbase + (size_t)(kt + 1) * 64 * DHE + (size_t)skey * DHE + sd;
      kv0 = *(const uint4*)(Kn);
      kv1 = *(const uint4*)(Kn + 32 * DHE);
      const u16* Vn = Vtbase + (kt + 1) * 64 + voct;
      vv0 = *(const uint4*)(Vn);
      vv1 = *(const uint4*)(Vn + 32);
    }
    __syncthreads();   // single barrier per iter (double-buffered)

    // ts fragments for this tile (B operand: value ts_key at k=key)
    {
      const u16* tst = tsb + kt * 64;
#pragma unroll
      for (int kh = 0; kh < 2; ++kh) {
        tsfr[kh].h[0] = *(const short4v*)(tst + kh * 32 + lq * 4);
        tsfr[kh].h[1] = *(const short4v*)(tst + kh * 32 + lq * 4 + 16);
      }
    }

    // K fragments once per tile, shared by all 4 q-quarters
    Frag kfr[4][2];
#pragma unroll
    for (int k2 = 0; k2 < 4; ++k2) {
#pragma unroll
      for (int f = 0; f < 2; ++f) {
        const short* p = &Kb[k2 * 16 + l16][f * 32 + lq * 4];
        kfr[k2][f].h[0] = *(const short4v*)p;
        kfr[k2][f].h[1] = *(const short4v*)(p + 16);
      }
    }

    auto qkq = [&](auto qc, f32x4 (&sc)[4]) {
      constexpr int qh = decltype(qc)::v;
      const float nm = -mrow[qh];
      f32x4 seed = {nm, nm, nm, nm};
#pragma unroll
      for (int k2 = 0; k2 < 4; ++k2) {
        f32x4 a = mfma16(kfr[k2][0], qf[qh][0], seed);
        sc[k2] = mfma16(kfr[k2][1], qf[qh][1], a);
      }
    };

    auto smq = [&](auto qc, f32x4 (&sc)[4]) {
      constexpr int qh = decltype(qc)::v;
      float hm[4];
#pragma unroll
      for (int k2 = 0; k2 < 4; ++k2) {
        const f32x4 s = sc[k2];
        hm[k2] = fmaxf(fmaxf(s[0], s[1]), fmaxf(s[2], s[3]));
      }
      float mx = fmaxf(fmaxf(hm[0], hm[1]), fmaxf(hm[2], hm[3]));
      mx = fmaxf(mx, __shfl_xor(mx, 16));
      mx = fmaxf(mx, __shfl_xor(mx, 32));
      if (__any(mx > 8.f)) {                 // wave-uniform rescale (rare)
        const float sh = fmaxf(mx, 0.f);     // never lower m
        const float al = exp2fast(-sh);
        mrow[qh] += sh;
        f32x4 alv;
#pragma unroll
        for (int r = 0; r < 4; ++r) alv[r] = __shfl(al, lq * 4 + r, 16);
#pragma unroll
        for (int dd = 0; dd < 4; ++dd) oacc[qh][dd] *= alv;
        lsum[qh] *= alv;
#pragma unroll
        for (int k2 = 0; k2 < 4; ++k2) sc[k2] -= sh;
      }
#pragma unroll
      for (int k2 = 0; k2 < 4; ++k2) {
        f32x4 s = sc[k2];
#pragma unroll
        for (int r = 0; r < 4; ++r) s[r] = exp2fast(s[r]);
        sc[k2] = s;
      }
      paf[qh][0].h[0] = pk4(sc[0]); paf[qh][0].h[1] = pk4(sc[1]);
      paf[qh][1].h[0] = pk4(sc[2]); paf[qh][1].h[1] = pk4(sc[3]);
      // lsum += sum_k ts_k * P_k (owner layout: reg r = q-row lq*4+r)
      lsum[qh] = mfma16(paf[qh][0], tsfr[0], lsum[qh]);
      lsum[qh] = mfma16(paf[qh][1], tsfr[1], lsum[qh]);
    };

    // quarter pipeline: SM(q) VALU/exp overlaps QK(q+1) MFMA cluster
    qkq(IC<0>{}, scA);
    qkq(IC<1>{}, scB);
    smq(IC<0>{}, scA);
    qkq(IC<2>{}, scA);
    smq(IC<1>{}, scB);
    qkq(IC<3>{}, scB);
    smq(IC<2>{}, scA);
    smq(IC<3>{}, scB);

    // O += P V' (V fragments read once, feed all 4 q-quarters)
    __builtin_amdgcn_s_setprio(1);
#pragma unroll
    for (int dd = 0; dd < 4; ++dd) {
      const int vrow = dd * 16 + l16;
      const int e = ((vrow >> 3) & 7) << 3;
#pragma unroll
      for (int kh = 0; kh < 2; ++kh) {
        Frag vb;
        vb.h[0] = *(const short4v*)&Vb[vrow][(kh * 32 + lq * 4) ^ e];
        vb.h[1] = *(const short4v*)&Vb[vrow][(kh * 32 + 16 + lq * 4) ^ e];
#pragma unroll
        for (int qh = 0; qh < 4; ++qh)
          oacc[qh][dd] = mfma16(paf[qh][kh], vb, oacc[qh][dd]);
      }
    }
    __builtin_amdgcn_s_setprio(0);
  }

  // write attn output merged-head [B][S][C] fp16 (lsum already owner-layout)
#pragma unroll
  for (int qh = 0; qh < 4; ++qh) {
    f32x4 linv;
#pragma unroll
    for (int r = 0; r < 4; ++r) linv[r] = 1.f / lsum[qh][r];
#pragma unroll
    for (int dd = 0; dd < 4; ++dd) {
#pragma unroll
      for (int r = 0; r < 4; ++r) {
        const int row = qb * 256 + wv * 64 + qh * 16 + lq * 4 + r;
        const float v = oacc[qh][dd][r] * linv[r];
        Out[((size_t)b * SEQ + row) * CDIM + h * DHE + dd * 16 + l16] = f2h(v);
      }
    }
  }
}

// ---- launcher ---------------------------------------------------------------

extern "C" void kernel_launch(void* const* d_in, const int* in_sizes, int n_in,
                              void* d_out, int out_size, void* d_ws, size_t ws_size,
                              hipStream_t stream) {
  const float* hs = (const float*)d_in[0];
  const float* Wq = (const float*)d_in[1];
  const float* Wk = (const float*)d_in[2];
  const float* Wv = (const float*)d_in[3];
  const float* Wo = (const float*)d_in[4];
  const float* bo = (const float*)d_in[5];
  const int* ts = (const int*)d_in[6];
  float* out = (float*)d_out;

  char* ws = (char*)d_ws;
  u16* xf = (u16*)(ws);                     // 16,777,216 B; reused as attn_out
  u16* wtq = (u16*)(ws + 16777216);         // q/k/v Wt contiguous -> one N=3072 GEMM
  u16* wtk = (u16*)(ws + 18874368);
  u16* wtv = (u16*)(ws + 20971520);
  u16* wto = (u16*)(ws + 23068672);
  u16* qbuf = (u16*)(ws + 25165824);        // q',k,V'^T contiguous (8,388,608 each)
  u16* kbuf = (u16*)(ws + 41943040);
  u16* vtbuf = (u16*)(ws + 58720256);       // V'^T [bh][d][s]
  u16* ts16 = (u16*)(ws + 75497472);        // ts fp16 [B][S]

  // fused prep: cast x (4096 blocks) + transpose W's (1024) + cast ts (32)
  prep_kernel<<<5152, 256, 0, stream>>>(hs, xf, Wq, Wk, Wv, Wo,
                                        wtq, wtk, wtv, wto, ts, ts16);

  // fused QKV projection (q pre-scaled, V' = ts*V written transposed)
  gemm_f16<0, 24><<<dim3(24, 64), 256, 0, stream>>>(xf, wtq, (void*)qbuf, nullptr, ts);

  attn_kernel<<<512, 256, 0, stream>>>(qbuf, kbuf, vtbuf, ts16, xf);

  // output projection + bias
  gemm_f16<1, 8><<<dim3(8, 64), 256, 0, stream>>>(xf, wto, (void*)out, bo, nullptr);

  (void)in_sizes; (void)n_in; (void)out_size; (void)ws_size;
}